// Round 15
// baseline (161.741 us; speedup 1.0000x reference)
//
#include <hip/hip_runtime.h>

#define NGRAPHS 512
#define D 64
#define NCLS 10
#define MAXDEG 64          // Poisson(16) max indegree; P(deg>63)*N ~ 1e-15 — safe pad
#define MDSH 6             // log2(MAXDEG)

// ---- indegree histogram; atomic return value IS the edge's within-node rank ----
__global__ void k_deg(const int* __restrict__ dst, int* __restrict__ degi,
                      int* __restrict__ rank, int E) {
  int i = blockIdx.x * blockDim.x + threadIdx.x;
  if (i < E) rank[i] = atomicAdd(&degi[dst[i]], 1);
}

// ---- fused dispatch 2 (everything that only needs k_deg done):
//      blocks [0,fillBlocks):               ELL fill ec2[dst*64+rank] = {src, tok[src]}
//      blocks [fillBlocks, +disBlocks):     dis = rsqrt(deg+1)
//      remaining blocks:                    ht[v] = emb[v] @ W1  (1000 rows, L2-resident)
__global__ __launch_bounds__(256) void k_fused2(
    const int* __restrict__ src, const int* __restrict__ dst,
    const int* __restrict__ rank, const int* __restrict__ tokens,
    int2* __restrict__ ec2, int E,
    const int* __restrict__ degi, float* __restrict__ dis, int n,
    const float* __restrict__ emb, const float* __restrict__ W1,
    float4* __restrict__ ht4, int ntok, int fillBlocks, int disBlocks,
    int tokBlocks) {
  if (blockIdx.x < fillBlocks) {
    int e = blockIdx.x * 256 + threadIdx.x;
    if (e < E) {
      int s = src[e];
      int rk = rank[e];
      if (rk < MAXDEG)
        ec2[((size_t)dst[e] << MDSH) + rk] = make_int2(s, tokens[s]);
    }
    return;
  }
  if (blockIdx.x < fillBlocks + disBlocks) {
    int i = (blockIdx.x - fillBlocks) * 256 + threadIdx.x;
    if (i < n) dis[i] = rsqrtf((float)degi[i] + 1.0f);
    return;
  }
  // token GEMM: wave per token row; lane=(slot[2b],cg[4b]); slot partitions K
  __shared__ float Ws[64 * 64];
  int tid = threadIdx.x;
  for (int i = tid; i < 64 * 64; i += 256) Ws[i] = W1[i];
  __syncthreads();
  const float4* Ws4 = (const float4*)Ws;
  int w = tid >> 6, lane = tid & 63;
  int cg = lane & 15;
  int kb = lane & 48;
  int bid = blockIdx.x - fillBlocks - disBlocks;
  for (int tok = bid * 4 + w; tok < ntok; tok += tokBlocks * 4) {
    float xval = emb[(size_t)tok * D + lane];
    float4 acc = make_float4(0.f, 0.f, 0.f, 0.f);
#pragma unroll
    for (int p = 0; p < 16; ++p) {
      float xv = __shfl(xval, kb + p, 64);
      float4 wv = Ws4[(kb + p) * 16 + cg];
      acc.x += xv * wv.x; acc.y += xv * wv.y;
      acc.z += xv * wv.z; acc.w += xv * wv.w;
    }
    acc.x += __shfl_xor(acc.x, 16, 64); acc.y += __shfl_xor(acc.y, 16, 64);
    acc.z += __shfl_xor(acc.z, 16, 64); acc.w += __shfl_xor(acc.w, 16, 64);
    acc.x += __shfl_xor(acc.x, 32, 64); acc.y += __shfl_xor(acc.y, 32, 64);
    acc.z += __shfl_xor(acc.z, 32, 64); acc.w += __shfl_xor(acc.w, 32, 64);
    if (lane < 16) ht4[(size_t)tok * 16 + cg] = acc;
  }
}

// ---- layer-1 aggregate over ht (L2-resident) + fused epilogue -> x2' (carries dis):
//      x2'[d] = dis[d] * relu( b1 + dis[d]*(sum_s dis[s]*ht[tok[s]] + dis[d]*ht[tok[d]]) )
//      R11-proven inner loop: 16 edges/trip, stride-4 tail, no predication. ----
__global__ __launch_bounds__(256) void k_agg1t(const float4* __restrict__ ht4,
                                               const int2* __restrict__ ec2,
                                               const int* __restrict__ degi,
                                               const int* __restrict__ tokens,
                                               const float* __restrict__ dis,
                                               const float4* __restrict__ b14,
                                               float4* __restrict__ out, int n) {
  int tid = blockIdx.x * blockDim.x + threadIdx.x;
  int node = tid >> 6;
  int lane = tid & 63;
  int slot = lane >> 4;
  int cg = lane & 15;
  if (node >= n) return;
  int beg = node << MDSH;
  int end = beg + min(degi[node], MAXDEG);
  float4 acc = make_float4(0.f, 0.f, 0.f, 0.f);
  int j = beg + slot;
  for (; j + 12 < end; j += 16) {       // 4 edges per slot per trip
    int2 e0 = ec2[j], e1 = ec2[j + 4], e2 = ec2[j + 8], e3 = ec2[j + 12];
    float w0 = dis[e0.x], w1 = dis[e1.x], w2 = dis[e2.x], w3 = dis[e3.x];
    float4 v0 = ht4[((size_t)e0.y << 4) + cg];
    float4 v1 = ht4[((size_t)e1.y << 4) + cg];
    float4 v2 = ht4[((size_t)e2.y << 4) + cg];
    float4 v3 = ht4[((size_t)e3.y << 4) + cg];
    acc.x += w0 * v0.x + w1 * v1.x + w2 * v2.x + w3 * v3.x;
    acc.y += w0 * v0.y + w1 * v1.y + w2 * v2.y + w3 * v3.y;
    acc.z += w0 * v0.z + w1 * v1.z + w2 * v2.z + w3 * v3.z;
    acc.w += w0 * v0.w + w1 * v1.w + w2 * v2.w + w3 * v3.w;
  }
  for (; j < end; j += 4) {
    int2 e = ec2[j];
    float w = dis[e.x];
    float4 v = ht4[((size_t)e.y << 4) + cg];
    acc.x += w * v.x; acc.y += w * v.y; acc.z += w * v.z; acc.w += w * v.w;
  }
  acc.x += __shfl_xor(acc.x, 16, 64); acc.y += __shfl_xor(acc.y, 16, 64);
  acc.z += __shfl_xor(acc.z, 16, 64); acc.w += __shfl_xor(acc.w, 16, 64);
  acc.x += __shfl_xor(acc.x, 32, 64); acc.y += __shfl_xor(acc.y, 32, 64);
  acc.z += __shfl_xor(acc.z, 32, 64); acc.w += __shfl_xor(acc.w, 32, 64);
  if (slot == 0) {
    float dd = dis[node];
    float4 vd = ht4[((size_t)tokens[node] << 4) + cg];
    float4 bv = b14[cg];
    float4 r;
    r.x = dd * fmaxf(dd * (acc.x + dd * vd.x) + bv.x, 0.f);
    r.y = dd * fmaxf(dd * (acc.y + dd * vd.y) + bv.y, 0.f);
    r.z = dd * fmaxf(dd * (acc.z + dd * vd.z) + bv.z, 0.f);
    r.w = dd * fmaxf(dd * (acc.w + dd * vd.w) + bv.w, 0.f);
    out[((size_t)node << 4) + cg] = r;
  }
}

// ---- layer-2 aggregate: z[d] = sum_s x2'[s] + x2'[d]  (pure sum; GEMM commuted
//      into the pool kernel). R11-proven inner loop. ----
__global__ __launch_bounds__(256) void k_aggz(const float4* __restrict__ h4,
                                              const int2* __restrict__ ec2,
                                              const int* __restrict__ degi,
                                              float4* __restrict__ out, int n) {
  int tid = blockIdx.x * blockDim.x + threadIdx.x;
  int node = tid >> 6;
  int lane = tid & 63;
  int slot = lane >> 4;
  int cg = lane & 15;
  if (node >= n) return;
  int beg = node << MDSH;
  int end = beg + min(degi[node], MAXDEG);
  float4 acc = make_float4(0.f, 0.f, 0.f, 0.f);
  int i = beg + slot;
  for (; i + 12 < end; i += 16) {
    int s0 = ec2[i].x, s1 = ec2[i + 4].x, s2 = ec2[i + 8].x, s3 = ec2[i + 12].x;
    float4 v0 = h4[((size_t)s0 << 4) + cg];
    float4 v1 = h4[((size_t)s1 << 4) + cg];
    float4 v2 = h4[((size_t)s2 << 4) + cg];
    float4 v3 = h4[((size_t)s3 << 4) + cg];
    acc.x += (v0.x + v1.x) + (v2.x + v3.x);
    acc.y += (v0.y + v1.y) + (v2.y + v3.y);
    acc.z += (v0.z + v1.z) + (v2.z + v3.z);
    acc.w += (v0.w + v1.w) + (v2.w + v3.w);
  }
  for (; i < end; i += 4) {
    float4 v = h4[((size_t)ec2[i].x << 4) + cg];
    acc.x += v.x; acc.y += v.y; acc.z += v.z; acc.w += v.w;
  }
  acc.x += __shfl_xor(acc.x, 16, 64); acc.y += __shfl_xor(acc.y, 16, 64);
  acc.z += __shfl_xor(acc.z, 16, 64); acc.w += __shfl_xor(acc.w, 16, 64);
  acc.x += __shfl_xor(acc.x, 32, 64); acc.y += __shfl_xor(acc.y, 32, 64);
  acc.z += __shfl_xor(acc.z, 32, 64); acc.w += __shfl_xor(acc.w, 32, 64);
  if (slot == 0) {
    float4 hv = h4[((size_t)node << 4) + cg];   // self term
    acc.x += hv.x; acc.y += hv.y; acc.z += hv.z; acc.w += hv.w;
    out[((size_t)node << 4) + cg] = acc;
  }
}

// ---- fused W2-GEMM + epilogue + mean-pool + head: one block per graph.
//      x3[d] = relu( dis[d]*(z[d] @ W2) + b2 ) computed on the fly; never stored. ----
__device__ __forceinline__ int lower_bound(const int* __restrict__ a, int n, int v) {
  int lo = 0, hi = n;
  while (lo < hi) {
    int m = (lo + hi) >> 1;
    if (a[m] < v) lo = m + 1; else hi = m;
  }
  return lo;
}

__global__ __launch_bounds__(256) void k_poolgemm(const float* __restrict__ z,
                                                  const int* __restrict__ batch,
                                                  const float* __restrict__ dis,
                                                  const float* __restrict__ W2,
                                                  const float* __restrict__ b2,
                                                  const float* __restrict__ lw,
                                                  const float* __restrict__ lb,
                                                  float* __restrict__ out, int n) {
  __shared__ float Ws[64 * 64];
  __shared__ float4 red4[4][16];
  __shared__ float pooled[64];
  int tid = threadIdx.x;
  for (int i = tid; i < 64 * 64; i += 256) Ws[i] = W2[i];
  __syncthreads();
  const float4* Ws4 = (const float4*)Ws;
  int g = blockIdx.x;
  int s = lower_bound(batch, n, g);
  int e = lower_bound(batch, n, g + 1);
  int w = tid >> 6, lane = tid & 63;
  int cg = lane & 15;
  int kb = lane & 48;
  float4 pacc = make_float4(0.f, 0.f, 0.f, 0.f);
  float4 bv = ((const float4*)b2)[cg];
  for (int node = s + w; node < e; node += 4) {
    float xval = z[(size_t)node * D + lane];
    float4 acc = make_float4(0.f, 0.f, 0.f, 0.f);
#pragma unroll
    for (int p = 0; p < 16; ++p) {
      float xv = __shfl(xval, kb + p, 64);
      float4 wv = Ws4[(kb + p) * 16 + cg];
      acc.x += xv * wv.x; acc.y += xv * wv.y;
      acc.z += xv * wv.z; acc.w += xv * wv.w;
    }
    acc.x += __shfl_xor(acc.x, 16, 64); acc.y += __shfl_xor(acc.y, 16, 64);
    acc.z += __shfl_xor(acc.z, 16, 64); acc.w += __shfl_xor(acc.w, 16, 64);
    acc.x += __shfl_xor(acc.x, 32, 64); acc.y += __shfl_xor(acc.y, 32, 64);
    acc.z += __shfl_xor(acc.z, 32, 64); acc.w += __shfl_xor(acc.w, 32, 64);
    float dd = dis[node];
    pacc.x += fmaxf(dd * acc.x + bv.x, 0.f);
    pacc.y += fmaxf(dd * acc.y + bv.y, 0.f);
    pacc.z += fmaxf(dd * acc.z + bv.z, 0.f);
    pacc.w += fmaxf(dd * acc.w + bv.w, 0.f);
  }
  if ((lane >> 4) == 0) red4[w][cg] = pacc;   // all slots identical; slot 0 writes
  __syncthreads();
  if (tid < 64) {
    const float* r0 = (const float*)&red4[0][0];
    const float* r1 = (const float*)&red4[1][0];
    const float* r2 = (const float*)&red4[2][0];
    const float* r3 = (const float*)&red4[3][0];
    float v = r0[tid] + r1[tid] + r2[tid] + r3[tid];
    pooled[tid] = v / fmaxf((float)(e - s), 1.0f);
  }
  __syncthreads();
  if (tid < NCLS) {
    int c = tid;
    float a = lb[c];
#pragma unroll
    for (int k = 0; k < D; ++k) a += pooled[k] * lw[k * NCLS + c];
    out[g * NCLS + c] = a;
  }
}

extern "C" void kernel_launch(void* const* d_in, const int* in_sizes, int n_in,
                              void* d_out, int out_size, void* d_ws, size_t ws_size,
                              hipStream_t stream) {
  const int* tokens = (const int*)d_in[0];
  const int* edge   = (const int*)d_in[1];
  const int* batch  = (const int*)d_in[2];
  const float* emb  = (const float*)d_in[3];
  const float* W1   = (const float*)d_in[4];
  const float* b1   = (const float*)d_in[5];
  const float* W2   = (const float*)d_in[6];
  const float* b2   = (const float*)d_in[7];
  const float* lw   = (const float*)d_in[8];
  const float* lb   = (const float*)d_in[9];
  float* out = (float*)d_out;

  const int N = in_sizes[0];
  const int E = in_sizes[1] / 2;
  const int ntok = in_sizes[3] / D;
  const int* src  = edge;
  const int* dstv = edge + E;

  char* ws = (char*)d_ws;
  size_t off = 0;
  auto alloc = [&](size_t bytes) {
    void* p = ws + off;
    off += (bytes + 255) & ~(size_t)255;
    return p;
  };
  float* A    = (float*)alloc((size_t)N * D * sizeof(float));        // z
  float* B    = (float*)alloc((size_t)N * D * sizeof(float));        // x2'
  int2*  ec2  = (int2*)alloc((size_t)N * MAXDEG * sizeof(int2));      // ELL {src, tok}
  int*   rank = (int*)alloc((size_t)E * sizeof(int));                 // within-node slot
  float* dis  = (float*)alloc((size_t)N * sizeof(float));
  int*   degi = (int*)alloc((size_t)N * sizeof(int));
  float* ht   = (float*)alloc((size_t)ntok * D * sizeof(float));      // emb @ W1

  hipMemsetAsync(degi, 0, (size_t)N * sizeof(int), stream);

  // 1) indegree + per-edge rank
  k_deg<<<(E + 255) / 256, 256, 0, stream>>>(dstv, degi, rank, E);

  // 2) fused: ELL fill + dis + token GEMM (ht = emb @ W1)
  const int fillBlocks = (E + 255) / 256;
  const int disBlocks = (N + 255) / 256;
  const int tokBlocks = (ntok + 3) / 4;
  k_fused2<<<fillBlocks + disBlocks + tokBlocks, 256, 0, stream>>>(
      src, dstv, rank, tokens, ec2, E, degi, dis, N, emb, W1, (float4*)ht, ntok,
      fillBlocks, disBlocks, tokBlocks);

  const int nodeBlocks = (N + 3) / 4;

  // 3) layer-1 aggregate (token-space, L2-resident) -> x2' in B
  k_agg1t<<<nodeBlocks, 256, 0, stream>>>((const float4*)ht, ec2, degi, tokens,
                                          dis, (const float4*)b1, (float4*)B, N);

  // 4) layer-2 aggregate (pure sum of x2') -> z in A
  k_aggz<<<nodeBlocks, 256, 0, stream>>>((const float4*)B, ec2, degi, (float4*)A, N);

  // 5) fused W2-GEMM + epilogue + mean-pool + head
  k_poolgemm<<<NGRAPHS, 256, 0, stream>>>(A, batch, dis, W2, b2, lw, lb, out, N);
}

// Round 16
// 151.421 us; speedup vs baseline: 1.0682x; 1.0682x over previous
//
#include <hip/hip_runtime.h>

#define NGRAPHS 512
#define D 64
#define NCLS 10
#define MAXDEG 64          // Poisson(16) max indegree; P(deg>63)*N ~ 1e-15 — safe pad
#define MDSH 6             // log2(MAXDEG)

// ---- fused dispatch 1: blocks [0,fillBlocks): indegree atomic + ELL fill in one pass
//      (atomic return IS the slot); remaining blocks: ht[v] = emb[v] @ W1 ----
__global__ __launch_bounds__(256) void k_degfill(
    const int* __restrict__ src, const int* __restrict__ dst,
    const int* __restrict__ tokens, int* __restrict__ degi,
    int2* __restrict__ ec2, int E,
    const float* __restrict__ emb, const float* __restrict__ W1,
    float4* __restrict__ ht4, int ntok, int fillBlocks, int tokBlocks) {
  if (blockIdx.x < fillBlocks) {
    int e = blockIdx.x * 256 + threadIdx.x;
    if (e < E) {
      int d = dst[e];
      int s = src[e];
      int rk = atomicAdd(&degi[d], 1);
      if (rk < MAXDEG)
        ec2[((size_t)d << MDSH) + rk] = make_int2(s, tokens[s]);
    }
    return;
  }
  // token GEMM: wave per token row; lane=(slot[2b],cg[4b]); slot partitions K
  __shared__ float Ws[64 * 64];
  int tid = threadIdx.x;
  for (int i = tid; i < 64 * 64; i += 256) Ws[i] = W1[i];
  __syncthreads();
  const float4* Ws4 = (const float4*)Ws;
  int w = tid >> 6, lane = tid & 63;
  int cg = lane & 15;
  int kb = lane & 48;
  int bid = blockIdx.x - fillBlocks;
  for (int tok = bid * 4 + w; tok < ntok; tok += tokBlocks * 4) {
    float xval = emb[(size_t)tok * D + lane];
    float4 acc = make_float4(0.f, 0.f, 0.f, 0.f);
#pragma unroll
    for (int p = 0; p < 16; ++p) {
      float xv = __shfl(xval, kb + p, 64);
      float4 wv = Ws4[(kb + p) * 16 + cg];
      acc.x += xv * wv.x; acc.y += xv * wv.y;
      acc.z += xv * wv.z; acc.w += xv * wv.w;
    }
    acc.x += __shfl_xor(acc.x, 16, 64); acc.y += __shfl_xor(acc.y, 16, 64);
    acc.z += __shfl_xor(acc.z, 16, 64); acc.w += __shfl_xor(acc.w, 16, 64);
    acc.x += __shfl_xor(acc.x, 32, 64); acc.y += __shfl_xor(acc.y, 32, 64);
    acc.z += __shfl_xor(acc.z, 32, 64); acc.w += __shfl_xor(acc.w, 32, 64);
    if (lane < 16) ht4[(size_t)tok * 16 + cg] = acc;
  }
}

// ---- layer-1 aggregate over ht (L2-resident) + fused epilogue -> x2' (carries dis).
//      dis computed on the fly from degi. R11-proven loop: 16 edges/trip, no predication ----
__global__ __launch_bounds__(256) void k_agg1t(const float4* __restrict__ ht4,
                                               const int2* __restrict__ ec2,
                                               const int* __restrict__ degi,
                                               const int* __restrict__ tokens,
                                               const float4* __restrict__ b14,
                                               float4* __restrict__ out, int n) {
  int tid = blockIdx.x * blockDim.x + threadIdx.x;
  int node = tid >> 6;
  int lane = tid & 63;
  int slot = lane >> 4;
  int cg = lane & 15;
  if (node >= n) return;
  int deg = min(degi[node], MAXDEG);
  int beg = node << MDSH;
  int end = beg + deg;
  float4 acc = make_float4(0.f, 0.f, 0.f, 0.f);
  int j = beg + slot;
  for (; j + 12 < end; j += 16) {       // 4 edges per slot per trip
    int2 e0 = ec2[j], e1 = ec2[j + 4], e2 = ec2[j + 8], e3 = ec2[j + 12];
    float w0 = rsqrtf((float)degi[e0.x] + 1.0f);
    float w1 = rsqrtf((float)degi[e1.x] + 1.0f);
    float w2 = rsqrtf((float)degi[e2.x] + 1.0f);
    float w3 = rsqrtf((float)degi[e3.x] + 1.0f);
    float4 v0 = ht4[((size_t)e0.y << 4) + cg];
    float4 v1 = ht4[((size_t)e1.y << 4) + cg];
    float4 v2 = ht4[((size_t)e2.y << 4) + cg];
    float4 v3 = ht4[((size_t)e3.y << 4) + cg];
    acc.x += w0 * v0.x + w1 * v1.x + w2 * v2.x + w3 * v3.x;
    acc.y += w0 * v0.y + w1 * v1.y + w2 * v2.y + w3 * v3.y;
    acc.z += w0 * v0.z + w1 * v1.z + w2 * v2.z + w3 * v3.z;
    acc.w += w0 * v0.w + w1 * v1.w + w2 * v2.w + w3 * v3.w;
  }
  for (; j < end; j += 4) {
    int2 e = ec2[j];
    float w = rsqrtf((float)degi[e.x] + 1.0f);
    float4 v = ht4[((size_t)e.y << 4) + cg];
    acc.x += w * v.x; acc.y += w * v.y; acc.z += w * v.z; acc.w += w * v.w;
  }
  acc.x += __shfl_xor(acc.x, 16, 64); acc.y += __shfl_xor(acc.y, 16, 64);
  acc.z += __shfl_xor(acc.z, 16, 64); acc.w += __shfl_xor(acc.w, 16, 64);
  acc.x += __shfl_xor(acc.x, 32, 64); acc.y += __shfl_xor(acc.y, 32, 64);
  acc.z += __shfl_xor(acc.z, 32, 64); acc.w += __shfl_xor(acc.w, 32, 64);
  if (slot == 0) {
    float dd = rsqrtf((float)deg + 1.0f);
    float4 vd = ht4[((size_t)tokens[node] << 4) + cg];
    float4 bv = b14[cg];
    float4 r;
    r.x = dd * fmaxf(dd * (acc.x + dd * vd.x) + bv.x, 0.f);
    r.y = dd * fmaxf(dd * (acc.y + dd * vd.y) + bv.y, 0.f);
    r.z = dd * fmaxf(dd * (acc.z + dd * vd.z) + bv.z, 0.f);
    r.w = dd * fmaxf(dd * (acc.w + dd * vd.w) + bv.w, 0.f);
    out[((size_t)node << 4) + cg] = r;
  }
}

// ---- pure GEMM: h2' = x2' @ W2 (x2' carries dis; no bias/relu) ----
__global__ __launch_bounds__(256) void k_gemmp(const float* __restrict__ x,
                                               const float* __restrict__ W,
                                               float4* __restrict__ o4, int n) {
  __shared__ float Ws[64 * 64];
  int tid = threadIdx.x;
  for (int i = tid; i < 64 * 64; i += 256) Ws[i] = W[i];
  __syncthreads();
  const float4* Ws4 = (const float4*)Ws;
  int w = tid >> 6, lane = tid & 63;
  int cg = lane & 15;
  int kb = lane & 48;
  for (int node = blockIdx.x * 4 + w; node < n; node += gridDim.x * 4) {
    float xval = x[(size_t)node * D + lane];
    float4 acc = make_float4(0.f, 0.f, 0.f, 0.f);
#pragma unroll
    for (int p = 0; p < 16; ++p) {
      float xv = __shfl(xval, kb + p, 64);
      float4 wv = Ws4[(kb + p) * 16 + cg];
      acc.x += xv * wv.x; acc.y += xv * wv.y;
      acc.z += xv * wv.z; acc.w += xv * wv.w;
    }
    acc.x += __shfl_xor(acc.x, 16, 64); acc.y += __shfl_xor(acc.y, 16, 64);
    acc.z += __shfl_xor(acc.z, 16, 64); acc.w += __shfl_xor(acc.w, 16, 64);
    acc.x += __shfl_xor(acc.x, 32, 64); acc.y += __shfl_xor(acc.y, 32, 64);
    acc.z += __shfl_xor(acc.z, 32, 64); acc.w += __shfl_xor(acc.w, 32, 64);
    if (lane < 16) o4[(size_t)node * 16 + cg] = acc;
  }
}

// ---- layer-2 aggregate of h2' + fused epilogue -> x3 (dis on the fly) ----
__global__ __launch_bounds__(256) void k_aggs(const float4* __restrict__ h4,
                                              const int2* __restrict__ ec2,
                                              const int* __restrict__ degi,
                                              const float4* __restrict__ b24,
                                              float4* __restrict__ out, int n) {
  int tid = blockIdx.x * blockDim.x + threadIdx.x;
  int node = tid >> 6;
  int lane = tid & 63;
  int slot = lane >> 4;
  int cg = lane & 15;
  if (node >= n) return;
  int deg = min(degi[node], MAXDEG);
  int beg = node << MDSH;
  int end = beg + deg;
  float4 acc = make_float4(0.f, 0.f, 0.f, 0.f);
  int i = beg + slot;
  for (; i + 12 < end; i += 16) {
    int s0 = ec2[i].x, s1 = ec2[i + 4].x, s2 = ec2[i + 8].x, s3 = ec2[i + 12].x;
    float4 v0 = h4[((size_t)s0 << 4) + cg];
    float4 v1 = h4[((size_t)s1 << 4) + cg];
    float4 v2 = h4[((size_t)s2 << 4) + cg];
    float4 v3 = h4[((size_t)s3 << 4) + cg];
    acc.x += (v0.x + v1.x) + (v2.x + v3.x);
    acc.y += (v0.y + v1.y) + (v2.y + v3.y);
    acc.z += (v0.z + v1.z) + (v2.z + v3.z);
    acc.w += (v0.w + v1.w) + (v2.w + v3.w);
  }
  for (; i < end; i += 4) {
    float4 v = h4[((size_t)ec2[i].x << 4) + cg];
    acc.x += v.x; acc.y += v.y; acc.z += v.z; acc.w += v.w;
  }
  acc.x += __shfl_xor(acc.x, 16, 64); acc.y += __shfl_xor(acc.y, 16, 64);
  acc.z += __shfl_xor(acc.z, 16, 64); acc.w += __shfl_xor(acc.w, 16, 64);
  acc.x += __shfl_xor(acc.x, 32, 64); acc.y += __shfl_xor(acc.y, 32, 64);
  acc.z += __shfl_xor(acc.z, 32, 64); acc.w += __shfl_xor(acc.w, 32, 64);
  if (slot == 0) {
    float dd = rsqrtf((float)deg + 1.0f);
    float4 hv = h4[((size_t)node << 4) + cg];
    float4 bv = b24[cg];
    acc.x = fmaxf(dd * (acc.x + hv.x) + bv.x, 0.f);
    acc.y = fmaxf(dd * (acc.y + hv.y) + bv.y, 0.f);
    acc.z = fmaxf(dd * (acc.z + hv.z) + bv.z, 0.f);
    acc.w = fmaxf(dd * (acc.w + hv.w) + bv.w, 0.f);
    out[((size_t)node << 4) + cg] = acc;
  }
}

// ---- fused mean-pool + linear head: one block per graph ----
__device__ __forceinline__ int lower_bound(const int* __restrict__ a, int n, int v) {
  int lo = 0, hi = n;
  while (lo < hi) {
    int m = (lo + hi) >> 1;
    if (a[m] < v) lo = m + 1; else hi = m;
  }
  return lo;
}

__global__ __launch_bounds__(256) void k_poolfinal(const float* __restrict__ x,
                                                   const int* __restrict__ batch,
                                                   const float* __restrict__ lw,
                                                   const float* __restrict__ lb,
                                                   float* __restrict__ out, int n) {
  __shared__ float red[4][64];
  __shared__ float pooled[64];
  int g = blockIdx.x;
  int s = lower_bound(batch, n, g);
  int e = lower_bound(batch, n, g + 1);
  int w = threadIdx.x >> 6, lane = threadIdx.x & 63;
  float acc = 0.f;
  for (int i = s + w; i < e; i += 4) acc += x[(size_t)i * D + lane];
  red[w][lane] = acc;
  __syncthreads();
  if (w == 0) {
    float v = red[0][lane] + red[1][lane] + red[2][lane] + red[3][lane];
    pooled[lane] = v / fmaxf((float)(e - s), 1.0f);
  }
  __syncthreads();
  if (threadIdx.x < NCLS) {
    int c = threadIdx.x;
    float a = lb[c];
#pragma unroll
    for (int k = 0; k < D; ++k) a += pooled[k] * lw[k * NCLS + c];
    out[g * NCLS + c] = a;
  }
}

extern "C" void kernel_launch(void* const* d_in, const int* in_sizes, int n_in,
                              void* d_out, int out_size, void* d_ws, size_t ws_size,
                              hipStream_t stream) {
  const int* tokens = (const int*)d_in[0];
  const int* edge   = (const int*)d_in[1];
  const int* batch  = (const int*)d_in[2];
  const float* emb  = (const float*)d_in[3];
  const float* W1   = (const float*)d_in[4];
  const float* b1   = (const float*)d_in[5];
  const float* W2   = (const float*)d_in[6];
  const float* b2   = (const float*)d_in[7];
  const float* lw   = (const float*)d_in[8];
  const float* lb   = (const float*)d_in[9];
  float* out = (float*)d_out;

  const int N = in_sizes[0];
  const int E = in_sizes[1] / 2;
  const int ntok = in_sizes[3] / D;
  const int* src  = edge;
  const int* dstv = edge + E;

  char* ws = (char*)d_ws;
  size_t off = 0;
  auto alloc = [&](size_t bytes) {
    void* p = ws + off;
    off += (bytes + 255) & ~(size_t)255;
    return p;
  };
  float* A    = (float*)alloc((size_t)N * D * sizeof(float));        // h2'
  float* B    = (float*)alloc((size_t)N * D * sizeof(float));        // x2' / x3
  int2*  ec2  = (int2*)alloc((size_t)N * MAXDEG * sizeof(int2));      // ELL {src, tok}
  int*   degi = (int*)alloc((size_t)N * sizeof(int));
  float* ht   = (float*)alloc((size_t)ntok * D * sizeof(float));      // emb @ W1

  hipMemsetAsync(degi, 0, (size_t)N * sizeof(int), stream);

  // 1) fused: indegree atomic + ELL fill (one E-pass) + token GEMM (ht = emb @ W1)
  const int fillBlocks = (E + 255) / 256;
  const int tokBlocks = (ntok + 3) / 4;
  k_degfill<<<fillBlocks + tokBlocks, 256, 0, stream>>>(
      src, dstv, tokens, degi, ec2, E, emb, W1, (float4*)ht, ntok,
      fillBlocks, tokBlocks);

  const int nodeBlocks = (N + 3) / 4;

  // 2) layer-1 aggregate (token-space, L2-resident; dis on the fly) -> x2' in B
  k_agg1t<<<nodeBlocks, 256, 0, stream>>>((const float4*)ht, ec2, degi, tokens,
                                          (const float4*)b1, (float4*)B, N);

  // 3) h2' = x2' @ W2 -> A
  k_gemmp<<<2048, 256, 0, stream>>>(B, W2, (float4*)A, N);

  // 4) layer-2 aggregate (dis on the fly) + epilogue -> x3 in B
  k_aggs<<<nodeBlocks, 256, 0, stream>>>((const float4*)A, ec2, degi,
                                         (const float4*)b2, (float4*)B, N);

  // 5) pooling + head
  k_poolfinal<<<NGRAPHS, 256, 0, stream>>>(B, batch, lw, lb, out, N);
}